// Round 1
// baseline (617.935 us; speedup 1.0000x reference)
//
#include <hip/hip_runtime.h>
#include <stdint.h>

typedef __attribute__((ext_vector_type(8))) short s16x8;
typedef __attribute__((ext_vector_type(4))) float f32x4;

#define BM 128
#define BN 128
#define BK 64

__device__ __forceinline__ short f2bf(float x) {
  uint32_t u = __builtin_bit_cast(uint32_t, x);
  u += 0x7FFFu + ((u >> 16) & 1u);   // round-to-nearest-even
  return (short)(u >> 16);
}

__device__ __forceinline__ void gload16(void* lds, const void* g) {
  __builtin_amdgcn_global_load_lds(
      (const __attribute__((address_space(1))) void*)g,
      (__attribute__((address_space(3))) void*)lds, 16, 0, 0);
}

__device__ __forceinline__ float gelu_tanh(float x) {
  // jax.nn.gelu default (approximate=True): 0.5x(1+tanh(sqrt(2/pi)(x+0.044715x^3)))
  // 0.5(1+tanh(u)) = e/(e+1) with e = exp(2u)  =>  gelu = x - x/(e+1)
  float u = 0.7978845608028654f * (x + 0.044715f * x * x * x);
  float e = __expf(2.0f * u);
  return x - x / (e + 1.0f);
}

// fp32 -> bf16 straight conversion (codebook)
__global__ void cvt_bf16(const float* __restrict__ in, short* __restrict__ out, int n8) {
  int t = blockIdx.x * 256 + threadIdx.x;
  if (t >= n8) return;
  const float* p = in + (size_t)t * 8;
  s16x8 o;
#pragma unroll
  for (int j = 0; j < 8; ++j) o[j] = f2bf(p[j]);
  *(s16x8*)(out + (size_t)t * 8) = o;
}

// in [K][N] fp32 -> out [N][K] bf16 (B^T for contiguous MFMA B-fragments)
__global__ void cvt_T(const float* __restrict__ in, short* __restrict__ out, int K, int N) {
  int Kb = K >> 3;
  int t = blockIdx.x * 256 + threadIdx.x;
  if (t >= N * Kb) return;
  int n = t / Kb;
  int k8 = (t - n * Kb) * 8;
  const float* s = in + (size_t)k8 * N + n;
  s16x8 o;
#pragma unroll
  for (int j = 0; j < 8; ++j) o[j] = f2bf(s[(size_t)j * N]);
  *(s16x8*)(out + (size_t)n * K + k8) = o;
}

// MODE 1: A = gathered codebook rows (idx), epilogue bias+GELU -> bf16 C
// MODE 2: A = plain bf16 rows,            epilogue bias       -> fp32 C
template <int MODE>
__global__ __launch_bounds__(256) void gemm_bf16(
    const short* __restrict__ Asrc, const int* __restrict__ idx,
    const short* __restrict__ Bt, const float* __restrict__ bias,
    void* __restrict__ Cv, int N, int K, int NBN) {
  __shared__ short Alds[BM * BK];  // [row][k], 16 KB
  __shared__ short Blds[BN * BK];  // [n][k],   16 KB

  const int nwg = gridDim.x;
  const int bid = blockIdx.x;
  int swz = bid;
  if ((nwg & 7) == 0) swz = (bid & 7) * (nwg >> 3) + (bid >> 3);  // XCD swizzle (bijective)
  const int bm = swz / NBN, bn = swz - (swz / NBN) * NBN;

  const int tid = threadIdx.x;
  const int wid = tid >> 6, lane = tid & 63;
  const int wr = wid >> 1, wc = wid & 1;

  // staging: 16 chunks of 1KB per tile; wave w owns chunks 4w..4w+3.
  // chunk cc covers 8 rows; lane l -> row cc*8 + (l>>3), col (l&7)*8 elems.
  const short* arow[4];
  const short* brow[4];
#pragma unroll
  for (int i = 0; i < 4; ++i) {
    const int cc = wid * 4 + i;
    const int r = cc * 8 + (lane >> 3);
    if (MODE == 1)
      arow[i] = Asrc + (size_t)idx[bm * BM + r] * (size_t)K;  // gather fused into staging
    else
      arow[i] = Asrc + (size_t)(bm * BM + r) * (size_t)K;
    brow[i] = Bt + (size_t)(bn * BN + r) * (size_t)K;
  }
  const int kl = (lane & 7) * 8;

  f32x4 acc[4][4] = {};

  for (int k0 = 0; k0 < K; k0 += BK) {
    __syncthreads();  // previous compute done before LDS overwrite
#pragma unroll
    for (int i = 0; i < 4; ++i) {
      const int cc = wid * 4 + i;
      gload16(&Alds[cc * 512], arow[i] + k0 + kl);
      gload16(&Blds[cc * 512], brow[i] + k0 + kl);
    }
    __syncthreads();  // compiler drains vmcnt(0) before barrier
#pragma unroll
    for (int ks = 0; ks < 2; ++ks) {
      const int lk = ks * 32 + (lane >> 4) * 8;
      const int lr = lane & 15;
      s16x8 a[4], b[4];
#pragma unroll
      for (int mi = 0; mi < 4; ++mi)
        a[mi] = *(const s16x8*)&Alds[(wr * 64 + mi * 16 + lr) * BK + lk];
#pragma unroll
      for (int ni = 0; ni < 4; ++ni)
        b[ni] = *(const s16x8*)&Blds[(wc * 64 + ni * 16 + lr) * BK + lk];
#pragma unroll
      for (int mi = 0; mi < 4; ++mi)
#pragma unroll
        for (int ni = 0; ni < 4; ++ni)
          acc[mi][ni] = __builtin_amdgcn_mfma_f32_16x16x32_bf16(a[mi], b[ni], acc[mi][ni], 0, 0, 0);
    }
  }

  // C/D layout (verified m89/m91): col = lane&15, row = (lane>>4)*4 + r
  const int mloc = bm * BM + wr * 64 + (lane >> 4) * 4;
  const int nloc = bn * BN + wc * 64 + (lane & 15);
#pragma unroll
  for (int ni = 0; ni < 4; ++ni) {
    const int n = nloc + ni * 16;
    const float bv = bias[n];
#pragma unroll
    for (int mi = 0; mi < 4; ++mi) {
      const int m = mloc + mi * 16;
      f32x4 v = acc[mi][ni];
#pragma unroll
      for (int r = 0; r < 4; ++r) {
        float x = v[r] + bv;
        if (MODE == 1) {
          x = gelu_tanh(x);
          ((short*)Cv)[(size_t)(m + r) * N + n] = f2bf(x);
        } else {
          ((float*)Cv)[(size_t)(m + r) * N + n] = x;
        }
      }
    }
  }
}

extern "C" void kernel_launch(void* const* d_in, const int* in_sizes, int n_in,
                              void* d_out, int out_size, void* d_ws, size_t ws_size,
                              hipStream_t stream) {
  const int* idx = (const int*)d_in[0];
  const float* cb = (const float*)d_in[1];
  const float* W1 = (const float*)d_in[2];
  const float* b1 = (const float*)d_in[3];
  const float* W2 = (const float*)d_in[4];
  const float* b2 = (const float*)d_in[5];
  float* out = (float*)d_out;

  // ws layout: cb_bf16 16MB | W1T 8MB | W2T 8MB | h-chunk (Mc*4096*2 B)
  char* ws = (char*)d_ws;
  short* cbb = (short*)(ws);
  short* w1t = (short*)(ws + (size_t)16 * 1024 * 1024);
  short* w2t = (short*)(ws + (size_t)24 * 1024 * 1024);
  short* h = (short*)(ws + (size_t)32 * 1024 * 1024);

  cvt_bf16<<<4096, 256, 0, stream>>>(cb, cbb, (8192 * 1024) / 8);
  cvt_T<<<2048, 256, 0, stream>>>(W1, w1t, 1024, 4096);  // -> [4096][1024]
  cvt_T<<<2048, 256, 0, stream>>>(W2, w2t, 4096, 1024);  // -> [1024][4096]

  const int Mtot = 32 * 576;  // 18432 tokens
  size_t avail = (ws_size > (size_t)32 * 1024 * 1024) ? ws_size - (size_t)32 * 1024 * 1024 : 0;
  int nc = 1;
  while (nc < 16 && (size_t)(Mtot / nc) * 8192 > avail) nc <<= 1;
  const int Mc = Mtot / nc;  // multiple of 128 for nc in {1,2,4,8,16}

  for (int c = 0; c < nc; ++c) {
    gemm_bf16<1><<<(Mc / 128) * (4096 / 128), 256, 0, stream>>>(
        cbb, idx + c * Mc, w1t, b1, (void*)h, 4096, 1024, 4096 / 128);
    gemm_bf16<2><<<(Mc / 128) * (1024 / 128), 256, 0, stream>>>(
        h, nullptr, w2t, b2, (void*)(out + (size_t)c * Mc * 1024), 1024, 4096, 1024 / 128);
  }
}

// Round 2
// 475.480 us; speedup vs baseline: 1.2996x; 1.2996x over previous
//
#include <hip/hip_runtime.h>
#include <stdint.h>

typedef __attribute__((ext_vector_type(8))) short s16x8;
typedef __attribute__((ext_vector_type(4))) float f32x4;

__device__ __forceinline__ short f2bf(float x) {
  uint32_t u = __builtin_bit_cast(uint32_t, x);
  u += 0x7FFFu + ((u >> 16) & 1u);  // RNE
  return (short)(u >> 16);
}

__device__ __forceinline__ void gload16(void* l, const void* g) {
  __builtin_amdgcn_global_load_lds(
      (const __attribute__((address_space(1))) void*)g,
      (__attribute__((address_space(3))) void*)l, 16, 0, 0);
}

__device__ __forceinline__ float gelu_tanh(float x) {
  float u = 0.7978845608028654f * (x + 0.044715f * x * x * x);
  float e = __expf(2.0f * u);
  return x - x / (e + 1.0f);
}

__global__ void cvt_bf16(const float* __restrict__ in, short* __restrict__ out, int n8) {
  int t = blockIdx.x * 256 + threadIdx.x;
  if (t >= n8) return;
  const float* p = in + (size_t)t * 8;
  s16x8 o;
#pragma unroll
  for (int j = 0; j < 8; ++j) o[j] = f2bf(p[j]);
  *(s16x8*)(out + (size_t)t * 8) = o;
}

__global__ void cvt_T(const float* __restrict__ in, short* __restrict__ out, int K, int N) {
  int Kb = K >> 3;
  int t = blockIdx.x * 256 + threadIdx.x;
  if (t >= N * Kb) return;
  int n = t / Kb;
  int k8 = (t - n * Kb) * 8;
  const float* s = in + (size_t)k8 * N + n;
  s16x8 o;
#pragma unroll
  for (int j = 0; j < 8; ++j) o[j] = f2bf(s[(size_t)j * N]);
  *(s16x8*)(out + (size_t)n * K + k8) = o;
}

// ---------------------------------------------------------------------------
// 8-phase-style 256x256x64 bf16 GEMM, 8 waves (2M x 4N), double-buffered LDS.
// Per K-tile: 4 quadrant phases; each phase stages 2 of the next tile's 8
// load-rounds into the OTHER buffer (no WAR), counted vmcnt(4)/vmcnt(2) sync.
// LDS XOR-swizzle (slot ^= row&7) via pre-swizzled global source + swizzled
// ds_read (both-sides rule). MODE 1: A rows gathered via idx, bias+GELU->bf16.
// MODE 2: plain A, bias -> fp32.
// ---------------------------------------------------------------------------
template <int MODE, int K, int N>
__global__ __launch_bounds__(512, 2) void gemm8p(
    const short* __restrict__ Asrc, const int* __restrict__ idx,
    const short* __restrict__ Bt, const float* __restrict__ bias,
    void* __restrict__ Cv) {
  __shared__ short lds[65536];  // 128 KiB: [buf0: A 16384 | B 16384][buf1: ...]

  constexpr int NBN = N / 256;
  const int nwg = gridDim.x;
  int swz = blockIdx.x;
  if ((nwg & 7) == 0) swz = (swz & 7) * (nwg >> 3) + (swz >> 3);  // XCD swizzle
  const int bm = swz / NBN, bn = swz - (swz / NBN) * NBN;

  const int tid = threadIdx.x;
  const int wid = tid >> 6, lane = tid & 63;
  const int wr = wid >> 2, wc = wid & 3;  // 2M x 4N waves; per-wave C: 128x64
  const int lr = lane & 15, hi = lane >> 4;

  // staging: round r = 64 rows (8 KB). thread -> row r*64 + tid/8, stored slot
  // tid&7; fetch logical slot (tid&7)^(row&7)  (inverse swizzle on source).
  const int sl = (tid & 7) ^ ((tid >> 3) & 7);
  const short* aptr[4];
  const short* bptr[4];
#pragma unroll
  for (int r = 0; r < 4; ++r) {
    int am = bm * 256 + r * 64 + (tid >> 3);
    long arow = (MODE == 1) ? (long)idx[am] : (long)am;
    aptr[r] = Asrc + arow * (long)K + sl * 8;
    bptr[r] = Bt + (long)(bn * 256 + r * 64 + (tid >> 3)) * K + sl * 8;
  }
  const int wlds = wid * 512;  // wave's 1KB lane-block inside a round

  // ds_read bases; slot for (ks,hi) is XOR-swizzled by row&7 (= lr&7 here)
  const int aRB = (wr * 128 + lr) * 64;
  const int bRB = 16384 + (wc * 64 + lr) * 64;
  const int sk0 = ((0 + hi) ^ (lr & 7)) * 8;
  const int sk1 = ((4 + hi) ^ (lr & 7)) * 8;

  f32x4 acc[8][4] = {};
  s16x8 af[4][2], bf[2][2][2];

  constexpr int NT = K >> 6;

  // prologue: tile 0 -> buf0, issue order B0,B1,B2,B3,A0,A2,A1,A3
#pragma unroll
  for (int r = 0; r < 4; ++r) gload16(&lds[16384 + r * 4096 + wlds], bptr[r]);
  gload16(&lds[0 * 4096 + wlds], aptr[0]);
  gload16(&lds[2 * 4096 + wlds], aptr[2]);
  gload16(&lds[1 * 4096 + wlds], aptr[1]);
  gload16(&lds[3 * 4096 + wlds], aptr[3]);
  asm volatile("s_waitcnt vmcnt(2)" ::: "memory");  // B*,A0,A2 landed; A1,A3 fly
  __builtin_amdgcn_s_barrier();

  for (int t = 0; t < NT; ++t) {
    const int cb = (t & 1) << 15;
    const int nb = cb ^ 32768;
    const int kt = ((t + 1 < NT) ? (t + 1) : 0) << 6;  // next tile k-offset (shorts)

    // ---- phase 1: quadrant (mq0,nq0); stage next B rounds 0,1 ----
#pragma unroll
    for (int mi = 0; mi < 4; ++mi) {
      af[mi][0] = *(const s16x8*)&lds[cb + aRB + mi * 1024 + sk0];
      af[mi][1] = *(const s16x8*)&lds[cb + aRB + mi * 1024 + sk1];
    }
#pragma unroll
    for (int ni = 0; ni < 2; ++ni) {
      bf[0][ni][0] = *(const s16x8*)&lds[cb + bRB + ni * 1024 + sk0];
      bf[0][ni][1] = *(const s16x8*)&lds[cb + bRB + ni * 1024 + sk1];
    }
    gload16(&lds[nb + 16384 + 0 * 4096 + wlds], bptr[0] + kt);
    gload16(&lds[nb + 16384 + 1 * 4096 + wlds], bptr[1] + kt);
    __builtin_amdgcn_s_barrier();
    asm volatile("s_waitcnt lgkmcnt(0)" ::: "memory");
    __builtin_amdgcn_s_setprio(1);
#pragma unroll
    for (int mi = 0; mi < 4; ++mi)
#pragma unroll
      for (int ni = 0; ni < 2; ++ni)
#pragma unroll
        for (int ks = 0; ks < 2; ++ks)
          acc[mi][ni] = __builtin_amdgcn_mfma_f32_16x16x32_bf16(af[mi][ks], bf[0][ni][ks], acc[mi][ni], 0, 0, 0);
    __builtin_amdgcn_s_setprio(0);
    __builtin_amdgcn_s_barrier();

    // ---- phase 2: (mq0,nq1); stage next B rounds 2,3; vmcnt(4) ----
#pragma unroll
    for (int ni = 0; ni < 2; ++ni) {
      bf[1][ni][0] = *(const s16x8*)&lds[cb + bRB + 2048 + ni * 1024 + sk0];
      bf[1][ni][1] = *(const s16x8*)&lds[cb + bRB + 2048 + ni * 1024 + sk1];
    }
    gload16(&lds[nb + 16384 + 2 * 4096 + wlds], bptr[2] + kt);
    gload16(&lds[nb + 16384 + 3 * 4096 + wlds], bptr[3] + kt);
    __builtin_amdgcn_s_barrier();
    asm volatile("s_waitcnt lgkmcnt(0)" ::: "memory");
    __builtin_amdgcn_s_setprio(1);
#pragma unroll
    for (int mi = 0; mi < 4; ++mi)
#pragma unroll
      for (int ni = 0; ni < 2; ++ni)
#pragma unroll
        for (int ks = 0; ks < 2; ++ks)
          acc[mi][2 + ni] = __builtin_amdgcn_mfma_f32_16x16x32_bf16(af[mi][ks], bf[1][ni][ks], acc[mi][2 + ni], 0, 0, 0);
    __builtin_amdgcn_s_setprio(0);
    asm volatile("s_waitcnt vmcnt(4)" ::: "memory");  // cur tile A1,A3 landed
    __builtin_amdgcn_s_barrier();

    // ---- phase 3: (mq1,nq0); stage next A rounds 0,2 ----
#pragma unroll
    for (int mi = 0; mi < 4; ++mi) {
      af[mi][0] = *(const s16x8*)&lds[cb + aRB + 4096 + mi * 1024 + sk0];
      af[mi][1] = *(const s16x8*)&lds[cb + aRB + 4096 + mi * 1024 + sk1];
    }
    gload16(&lds[nb + 0 * 4096 + wlds], aptr[0] + kt);
    gload16(&lds[nb + 2 * 4096 + wlds], aptr[2] + kt);
    __builtin_amdgcn_s_barrier();
    asm volatile("s_waitcnt lgkmcnt(0)" ::: "memory");
    __builtin_amdgcn_s_setprio(1);
#pragma unroll
    for (int mi = 0; mi < 4; ++mi)
#pragma unroll
      for (int ni = 0; ni < 2; ++ni)
#pragma unroll
        for (int ks = 0; ks < 2; ++ks)
          acc[4 + mi][ni] = __builtin_amdgcn_mfma_f32_16x16x32_bf16(af[mi][ks], bf[0][ni][ks], acc[4 + mi][ni], 0, 0, 0);
    __builtin_amdgcn_s_setprio(0);
    __builtin_amdgcn_s_barrier();

    // ---- phase 4: (mq1,nq1); stage next A rounds 1,3; vmcnt(2) ----
    gload16(&lds[nb + 1 * 4096 + wlds], aptr[1] + kt);
    gload16(&lds[nb + 3 * 4096 + wlds], aptr[3] + kt);
    __builtin_amdgcn_s_barrier();
    __builtin_amdgcn_s_setprio(1);
#pragma unroll
    for (int mi = 0; mi < 4; ++mi)
#pragma unroll
      for (int ni = 0; ni < 2; ++ni)
#pragma unroll
        for (int ks = 0; ks < 2; ++ks)
          acc[4 + mi][2 + ni] = __builtin_amdgcn_mfma_f32_16x16x32_bf16(af[mi][ks], bf[1][ni][ks], acc[4 + mi][2 + ni], 0, 0, 0);
    __builtin_amdgcn_s_setprio(0);
    asm volatile("s_waitcnt vmcnt(2)" ::: "memory");  // next tile: all but A1,A3
    __builtin_amdgcn_s_barrier();
  }

  // epilogue: C/D layout col=lane&15, row=(lane>>4)*4+r
  const int m0 = bm * 256 + wr * 128 + hi * 4;
  const int n0 = bn * 256 + wc * 64 + lr;
#pragma unroll
  for (int j = 0; j < 4; ++j) {
    const int n = n0 + j * 16;
    const float bv = bias[n];
#pragma unroll
    for (int i = 0; i < 8; ++i) {
      f32x4 v = acc[i][j];
#pragma unroll
      for (int r = 0; r < 4; ++r) {
        const int m = m0 + i * 16 + r;
        float x = v[r] + bv;
        if (MODE == 1) {
          ((short*)Cv)[(size_t)m * N + n] = f2bf(gelu_tanh(x));
        } else {
          ((float*)Cv)[(size_t)m * N + n] = x;
        }
      }
    }
  }
}

extern "C" void kernel_launch(void* const* d_in, const int* in_sizes, int n_in,
                              void* d_out, int out_size, void* d_ws, size_t ws_size,
                              hipStream_t stream) {
  const int* idx = (const int*)d_in[0];
  const float* cb = (const float*)d_in[1];
  const float* W1 = (const float*)d_in[2];
  const float* b1 = (const float*)d_in[3];
  const float* W2 = (const float*)d_in[4];
  const float* b2 = (const float*)d_in[5];
  float* out = (float*)d_out;

  char* ws = (char*)d_ws;
  short* cbb = (short*)(ws);
  short* w1t = (short*)(ws + (size_t)16 * 1024 * 1024);
  short* w2t = (short*)(ws + (size_t)24 * 1024 * 1024);
  short* h = (short*)(ws + (size_t)32 * 1024 * 1024);

  cvt_bf16<<<4096, 256, 0, stream>>>(cb, cbb, (8192 * 1024) / 8);
  cvt_T<<<2048, 256, 0, stream>>>(W1, w1t, 1024, 4096);  // -> [4096][1024]
  cvt_T<<<2048, 256, 0, stream>>>(W2, w2t, 4096, 1024);  // -> [1024][4096]

  const int Mtot = 32 * 576;  // 18432 = 72 * 256
  size_t avail = (ws_size > (size_t)32 * 1024 * 1024) ? ws_size - (size_t)32 * 1024 * 1024 : 0;
  int nc = 1;
  while (nc < 8 && (size_t)(Mtot / nc) * 8192 > avail) nc <<= 1;
  const int Mc = Mtot / nc;  // multiple of 256 for nc in {1,2,4,8}

  for (int c = 0; c < nc; ++c) {
    gemm8p<1, 1024, 4096><<<(Mc / 256) * 16, 512, 0, stream>>>(
        cbb, idx + c * Mc, w1t, b1, (void*)h);
    gemm8p<2, 4096, 1024><<<(Mc / 256) * 4, 512, 0, stream>>>(
        h, nullptr, w2t, b2, (void*)(out + (size_t)c * Mc * 1024));
  }
}